// Round 17
// baseline (255.612 us; speedup 1.0000x reference)
//
#include <hip/hip_runtime.h>
#include <hip/hip_bf16.h>
#include <math.h>

using bf16x8 = __attribute__((ext_vector_type(8))) short;
using f32x4  = __attribute__((ext_vector_type(4))) float;
using v4i    = __attribute__((ext_vector_type(4))) int;

#define NCH 64  // edge chunks per partition (r17: 32->64 for more atomic parallelism)
#define SCAN_B 1024

__device__ __forceinline__ float b2f(unsigned short u) {
    return __uint_as_float(((unsigned)u) << 16);
}
__device__ __forceinline__ unsigned short f2b(float f) {
    unsigned u = __float_as_uint(f);
    return (unsigned short)((u + 0x7fff + ((u >> 16) & 1)) >> 16);
}

// ---------------- fused prep: x->bf16, W->bf16^T, zero cnt ----------------
__global__ void k_prep(const float* __restrict__ x, unsigned short* __restrict__ xb, int n8,
                       const float* __restrict__ W1, const float* __restrict__ W2,
                       unsigned short* __restrict__ wt1, unsigned short* __restrict__ wt2,
                       unsigned* __restrict__ cnt, int ncnt, int nbx, int nbw) {
    int bid = blockIdx.x;
    if (bid < nbx) {
        int i = bid * 256 + threadIdx.x;
        if (i >= n8) return;
        float4 a = ((const float4*)x)[i * 2], b = ((const float4*)x)[i * 2 + 1];
        uint4 o;
        o.x = f2b(a.x) | ((unsigned)f2b(a.y) << 16);
        o.y = f2b(a.z) | ((unsigned)f2b(a.w) << 16);
        o.z = f2b(b.x) | ((unsigned)f2b(b.y) << 16);
        o.w = f2b(b.z) | ((unsigned)f2b(b.w) << 16);
        ((uint4*)xb)[i] = o;
    } else if (bid < nbx + nbw) {
        int i = (bid - nbx) * 256 + threadIdx.x;
        if (i < 32768) {
            int r = i >> 14, c = (i >> 7) & 127, k = i & 127;
            wt1[i] = f2b(W1[(r << 14) + (k << 7) + c]);
        } else {
            int j = i - 32768;
            if (j >= 16384) return;
            int r = j >> 13, c = (j >> 7) & 63, k = j & 127;
            wt2[j] = f2b(W2[r * 8192 + k * 64 + c]);
        }
    } else {
        int i = (bid - nbx - nbw) * 256 + threadIdx.x;
        if (i < ncnt) cnt[i] = 0u;
    }
}

// ---------------- histogram: XCD-partitioned, LDS-staged counts, coalesced flush ----------------
__global__ __launch_bounds__(256) void k_histp(const int* __restrict__ dst,
                                               unsigned* __restrict__ cnt, int E, int N) {
    __shared__ unsigned sm[6250];  // N/8 counters
    const int part = blockIdx.x & 7, chunk = blockIdx.x >> 3;
    const int r = blockIdx.y;
    const int P = N / 8;
    const int lo = part * P;
    for (int i = threadIdx.x; i < P; i += 256) sm[i] = 0u;
    __syncthreads();
    const int per = E / 32;   // keep hist at 32 chunks (proven config)
    const int e0 = chunk * per, e1 = e0 + per;
    const int* dr = dst + (size_t)r * E;
    for (int e = e0 + (int)threadIdx.x * 4; e < e1; e += 1024) {
        v4i d4 = *(const v4i*)(dr + e);
        int a0 = d4.x - lo, a1 = d4.y - lo, a2 = d4.z - lo, a3 = d4.w - lo;
        if ((unsigned)a0 < (unsigned)P) atomicAdd(&sm[a0], 1u);
        if ((unsigned)a1 < (unsigned)P) atomicAdd(&sm[a1], 1u);
        if ((unsigned)a2 < (unsigned)P) atomicAdd(&sm[a2], 1u);
        if ((unsigned)a3 < (unsigned)P) atomicAdd(&sm[a3], 1u);
    }
    __syncthreads();
    unsigned* cr = cnt + (size_t)r * N + lo;
    for (int i = threadIdx.x; i < P; i += 256) {
        unsigned v = sm[i];
        if (v) atomicAdd(&cr[i], v);
    }
}

// ---------------- scanA: per-1024-chunk sums ----------------
__global__ void k_scanA(const unsigned* __restrict__ cnt, unsigned* __restrict__ bsum,
                        int n, int nb) {
    int r = blockIdx.y, b = blockIdx.x;
    int i0 = b * SCAN_B;
    unsigned s = 0;
    for (int t = threadIdx.x; t < SCAN_B; t += 256) {
        int i = i0 + t;
        if (i < n) s += cnt[(size_t)r * n + i];
    }
    __shared__ unsigned red[256];
    red[threadIdx.x] = s; __syncthreads();
    for (int st = 128; st > 0; st >>= 1) {
        if ((int)threadIdx.x < st) red[threadIdx.x] += red[threadIdx.x + st];
        __syncthreads();
    }
    if (threadIdx.x == 0) bsum[r * nb + b] = red[0];
}

// ---------------- scanC2: inline block-prefix (scanB folded) + off + cursors ----------------
__global__ void k_scanC2(unsigned* __restrict__ cnt, const unsigned* __restrict__ bsum,
                         unsigned* __restrict__ off, int n, int nb) {
    int r = blockIdx.y, b = blockIdx.x;
    __shared__ unsigned sbase[65];
    if (threadIdx.x < 64) {
        int l = threadIdx.x;
        unsigned orig = (l < nb) ? bsum[r * nb + l] : 0u;
        unsigned v = orig;
        for (int st = 1; st < 64; st <<= 1) {
            unsigned t = __shfl_up(v, st);
            if (l >= st) v += t;
        }
        sbase[l] = v - orig;
        if (l == 63) sbase[64] = v;
    }
    __syncthreads();
    if (b == 0 && threadIdx.x == 0) off[(size_t)r * (n + 1) + n] = sbase[64];
    const unsigned base = sbase[b];
    int i0 = b * SCAN_B + (int)threadIdx.x * 4;
    unsigned v[4]; unsigned s = 0;
#pragma unroll
    for (int j = 0; j < 4; j++) {
        int i = i0 + j;
        v[j] = (i < n) ? cnt[(size_t)r * n + i] : 0u;
        s += v[j];
    }
    __shared__ unsigned red[256];
    red[threadIdx.x] = s; __syncthreads();
    for (int st = 1; st < 256; st <<= 1) {
        unsigned t = ((int)threadIdx.x >= st) ? red[threadIdx.x - st] : 0u;
        __syncthreads();
        red[threadIdx.x] += t;
        __syncthreads();
    }
    unsigned run = base + red[threadIdx.x] - s;
#pragma unroll
    for (int j = 0; j < 4; j++) {
        int i = i0 + j;
        if (i < n) {
            off[(size_t)r * (n + 1) + i] = run;
            cnt[(size_t)r * n + i] = run;  // cursor = absolute start slot
        }
        run += v[j];
    }
}

// ---------------- scatter body (XCD-partitioned, global cursors, NT u16 payload) ----------------
__device__ __forceinline__ void scat_body(int bid, const int* __restrict__ src,
                                          const int* __restrict__ dst, unsigned* __restrict__ cur,
                                          unsigned short* __restrict__ csr, int E, int N) {
    const int part = bid & 7;
    const int q = bid >> 3;
    const int r = q & 1, chunk = q >> 1;
    const int lo = part * (N / 8), hi = lo + N / 8;
    const int per = E / NCH;
    const int e0 = chunk * per, e1 = e0 + per;
    const int* dr = dst + (size_t)r * E;
    const int* sr = src + (size_t)r * E;
    unsigned* curr = cur + (size_t)r * N;
    unsigned short* csrr = csr + (size_t)r * E;
    for (int e = e0 + (int)threadIdx.x * 4; e < e1; e += 1024) {
        v4i d4 = *(const v4i*)(dr + e);
        bool m0 = (d4.x >= lo) & (d4.x < hi);
        bool m1 = (d4.y >= lo) & (d4.y < hi);
        bool m2 = (d4.z >= lo) & (d4.z < hi);
        bool m3 = (d4.w >= lo) & (d4.w < hi);
        if (m0 | m1 | m2 | m3) {
            v4i s4 = *(const v4i*)(sr + e);
            if (m0) { unsigned p = atomicAdd(&curr[d4.x], 1u);
                      __builtin_nontemporal_store((unsigned short)s4.x, &csrr[p]); }
            if (m1) { unsigned p = atomicAdd(&curr[d4.y], 1u);
                      __builtin_nontemporal_store((unsigned short)s4.y, &csrr[p]); }
            if (m2) { unsigned p = atomicAdd(&curr[d4.z], 1u);
                      __builtin_nontemporal_store((unsigned short)s4.z, &csrr[p]); }
            if (m3) { unsigned p = atomicAdd(&curr[d4.w], 1u);
                      __builtin_nontemporal_store((unsigned short)s4.w, &csrr[p]); }
        }
    }
}

// ---------------- MFMA GEMM body + fused el/er (LDS-staged) ----------------
template <int M, int H>
__device__ __forceinline__ void gemm_body(int xblk, int r,
        const unsigned short* __restrict__ Xb, const unsigned short* __restrict__ Wt0,
        const float* __restrict__ alv, const float* __restrict__ arv,
        unsigned short* __restrict__ feat0, float* __restrict__ el, float* __restrict__ er,
        int N, unsigned short* xs, unsigned short* ws) {
    constexpr int D = M / H;
    const unsigned short* Wt = Wt0 + (size_t)r * M * 128;
    unsigned short* outp = feat0 + (size_t)r * N * M;
    float* elr = el + (size_t)r * N * H;
    float* err = er + (size_t)r * N * H;
    const int tid = threadIdx.x;
    const int row0 = xblk * 64;
    for (int ch = tid; ch < 64 * 16; ch += 256) {
        int rr = ch >> 4, c16 = ch & 15;
        int gr = row0 + rr;
        uint4 v = make_uint4(0, 0, 0, 0);
        if (gr < N) v = ((const uint4*)(Xb + (size_t)gr * 128))[c16];
        int byte = rr * 256 + ((c16 * 16) ^ ((rr & 7) << 4));
        *(uint4*)((char*)xs + byte) = v;
    }
    for (int ch = tid; ch < M * 16; ch += 256) {
        int rr = ch >> 4, c16 = ch & 15;
        uint4 v = ((const uint4*)(Wt + (size_t)rr * 128))[c16];
        int byte = rr * 256 + ((c16 * 16) ^ ((rr & 7) << 4));
        *(uint4*)((char*)ws + byte) = v;
    }
    __syncthreads();
    const int w = tid >> 6, l = tid & 63;
    const int sub = l & 15;
    const int ar_ = w * 16 + sub;
    const int kg = l >> 4;
    bf16x8 a[4];
#pragma unroll
    for (int k4 = 0; k4 < 4; k4++) {
        int byte = ar_ * 256 + (((kg * 16) + k4 * 64) ^ ((ar_ & 7) << 4));
        a[k4] = *(const bf16x8*)((const char*)xs + byte);
    }
    float alr[M / 16], arr[M / 16];
#pragma unroll
    for (int ct = 0; ct < M / 16; ct++) {
        alr[ct] = alv[(size_t)r * M + ct * 16 + sub];
        arr[ct] = arv[(size_t)r * M + ct * 16 + sub];
    }
    float pel[H][4], per[H][4];
#pragma unroll
    for (int h = 0; h < H; h++)
#pragma unroll
        for (int q = 0; q < 4; q++) { pel[h][q] = 0.f; per[h][q] = 0.f; }

#pragma unroll
    for (int ct = 0; ct < M / 16; ct++) {
        f32x4 acc = {0.f, 0.f, 0.f, 0.f};
        const int bc = ct * 16 + sub;
#pragma unroll
        for (int k4 = 0; k4 < 4; k4++) {
            int byte = bc * 256 + (((kg * 16) + k4 * 64) ^ ((bc & 7) << 4));
            bf16x8 bfr = *(const bf16x8*)((const char*)ws + byte);
            acc = __builtin_amdgcn_mfma_f32_16x16x32_bf16(a[k4], bfr, acc, 0, 0, 0);
        }
        const int hct = (ct * 16) / D;
#pragma unroll
        for (int q = 0; q < 4; q++) {
            pel[hct][q] += acc[q] * alr[ct];
            per[hct][q] += acc[q] * arr[ct];
        }
#pragma unroll
        for (int q = 0; q < 4; q++) {
            int gr = row0 + w * 16 + kg * 4 + q;
            if (gr < N) outp[(size_t)gr * M + ct * 16 + sub] = f2b(acc[q]);
        }
    }
#pragma unroll
    for (int h = 0; h < H; h++)
#pragma unroll
        for (int q = 0; q < 4; q++) {
            float v = pel[h][q], u = per[h][q];
#pragma unroll
            for (int o = 8; o > 0; o >>= 1) { v += __shfl_xor(v, o); u += __shfl_xor(u, o); }
            pel[h][q] = v; per[h][q] = u;
        }
#pragma unroll
    for (int h = 0; h < H; h++) {
        if (sub == h) {
#pragma unroll
            for (int q = 0; q < 4; q++) {
                int gr = row0 + w * 16 + kg * 4 + q;
                if (gr < N) { elr[(size_t)gr * H + h] = pel[h][q]; err[(size_t)gr * H + h] = per[h][q]; }
            }
        }
    }
}

// ---------------- fused scatter + layer-1 GEMM ----------------
__global__ __launch_bounds__(256) void k_scatgemm(
    const int* __restrict__ src, const int* __restrict__ dst,
    unsigned* __restrict__ cur, unsigned short* __restrict__ csr, int E, int N, int scatBlocks,
    const unsigned short* __restrict__ Xb, const unsigned short* __restrict__ Wt0,
    const float* __restrict__ alv, const float* __restrict__ arv,
    unsigned short* __restrict__ feat0, float* __restrict__ el, float* __restrict__ er) {
    __shared__ __align__(16) unsigned short xs[64 * 128];
    __shared__ __align__(16) unsigned short ws[128 * 128];
    int bid = blockIdx.x;
    if (bid < scatBlocks) {
        scat_body(bid, src, dst, cur, csr, E, N);
    } else {
        int g = bid - scatBlocks;
        gemm_body<128, 4>(g >> 1, g & 1, Xb, Wt0, alv, arv, feat0, el, er, N, xs, ws);
    }
}

// ---------------- layer-2 GEMM ----------------
__global__ __launch_bounds__(256) void k_gemm2(
    const unsigned short* __restrict__ Xb, const unsigned short* __restrict__ Wt0,
    const float* __restrict__ alv, const float* __restrict__ arv,
    unsigned short* __restrict__ feat0, float* __restrict__ el, float* __restrict__ er, int N) {
    __shared__ __align__(16) unsigned short xs[64 * 128];
    __shared__ __align__(16) unsigned short ws[64 * 128];
    gemm_body<64, 1>(blockIdx.x, blockIdx.y, Xb, Wt0, alv, arv, feat0, el, er, N, xs, ws);
}

// ---------------- fused per-node GAT, layer 1 (H=4, D=32) ----------------
template <int ELUF>
__global__ __launch_bounds__(256) void k_node_gat1(
    const unsigned* __restrict__ off, const unsigned short* __restrict__ csr_src,
    const float* __restrict__ el, const float* __restrict__ er,
    const unsigned short* __restrict__ feat0, const unsigned short* __restrict__ feat1,
    const float* __restrict__ bias, unsigned* __restrict__ outp, int N, int E) {
    constexpr int H = 4, HD = 128;
    __shared__ float s_w[4][4 * 64];
    __shared__ int s_sid[4][64];
    const int wslot = threadIdx.x >> 6;
    const int lane = threadIdx.x & 63;
    const int n = (blockIdx.x * 256 + threadIdx.x) >> 6;
    if (n >= N) return;
    const int c0 = lane * 2;
    const int h = c0 / 32;
    const unsigned laneoff = (unsigned)lane << 2;

    float res[2] = {0.f, 0.f};

    for (int r = 0; r < 2; r++) {
        const char* __restrict__ featc = (const char*)(r ? feat1 : feat0);
        const float* elr = el + (size_t)r * N * H;
        const float* ernp = er + (size_t)r * N * H + (size_t)n * H;
        float ern[H];
#pragma unroll
        for (int hh = 0; hh < H; hh++) ern[hh] = ernp[hh];
        const unsigned* offr = off + (size_t)r * (N + 1);
        const unsigned short* srcs = csr_src + (size_t)r * E;
        const unsigned o0 = offr[n], o1 = offr[n + 1];

        float den = 0.f;
        float acc[2] = {0.f, 0.f};

        for (unsigned base = o0; base < o1; base += 64) {
            const int cnt = (int)min(64u, o1 - base);
            if (lane < cnt) {
                unsigned sv = srcs[base + lane];
                s_sid[wslot][lane] = (int)sv;
                float4 e4 = *(const float4*)(elr + (size_t)sv * 4);
                float v0 = e4.x + ern[0]; v0 = v0 > 0.f ? v0 : 0.2f * v0;
                float v1 = e4.y + ern[1]; v1 = v1 > 0.f ? v1 : 0.2f * v1;
                float v2 = e4.z + ern[2]; v2 = v2 > 0.f ? v2 : 0.2f * v2;
                float v3 = e4.w + ern[3]; v3 = v3 > 0.f ? v3 : 0.2f * v3;
                float4 wv = make_float4(__expf(v0), __expf(v1), __expf(v2), __expf(v3));
                *(float4*)&s_w[wslot][lane * 4] = wv;
            }
            asm volatile("s_waitcnt lgkmcnt(0)" ::: "memory");
#pragma unroll 8
            for (int j = 0; j < cnt; j++) {
                unsigned sv = (unsigned)s_sid[wslot][j];
                float wv = s_w[wslot][j * 4 + h];
                den += wv;
                unsigned u = *(const unsigned*)(featc + ((sv << 8) + laneoff));
                acc[0] += wv * __uint_as_float(u << 16);
                acc[1] += wv * __uint_as_float(u & 0xffff0000u);
            }
        }
        if (den > 0.f) {
            float inv = 1.f / den;
            res[0] += acc[0] * inv;
            res[1] += acc[1] * inv;
        }
    }
    float v0 = res[0] + bias[c0] + bias[HD + c0];
    float v1 = res[1] + bias[c0 + 1] + bias[HD + c0 + 1];
    if (ELUF) { v0 = v0 > 0.f ? v0 : expm1f(v0); v1 = v1 > 0.f ? v1 : expm1f(v1); }
    outp[((size_t)n * HD + c0) / 2] = f2b(v0) | ((unsigned)f2b(v1) << 16);
}

// ---------------- fused per-node GAT, layer 2 (H=1, D=64) — quad-processed ----------------
// 4 quarter-waves of 16 lanes; each quarter handles one edge per iteration
// (uint2 = 4 cols per lane); merge via shfl_xor(16) + shfl_xor(32).
__global__ __launch_bounds__(256) void k_node_gat2(
    const unsigned* __restrict__ off, const unsigned short* __restrict__ csr_src,
    const float* __restrict__ el, const float* __restrict__ er,
    const unsigned short* __restrict__ feat0, const unsigned short* __restrict__ feat1,
    const float* __restrict__ bias, float* __restrict__ outp, int N, int E) {
    __shared__ uint2 s_ws[4][64];  // {sid, w}
    const int wslot = threadIdx.x >> 6;
    const int lane = threadIdx.x & 63;
    const int n = (blockIdx.x * 256 + threadIdx.x) >> 6;
    if (n >= N) return;
    const int sub = lane & 15, quarter = lane >> 4;
    const unsigned laneoff = (unsigned)sub << 3;  // 4 cols (8B) per lane

    float res[4] = {0.f, 0.f, 0.f, 0.f};

    for (int r = 0; r < 2; r++) {
        const char* __restrict__ featc = (const char*)(r ? feat1 : feat0);
        const float* elr = el + (size_t)r * N;
        const float ern = er[(size_t)r * N + n];
        const unsigned* offr = off + (size_t)r * (N + 1);
        const unsigned short* srcs = csr_src + (size_t)r * E;
        const unsigned o0 = offr[n], o1 = offr[n + 1];

        float den = 0.f;
        float acc[4] = {0.f, 0.f, 0.f, 0.f};

        for (unsigned base = o0; base < o1; base += 64) {
            const int cnt = (int)min(64u, o1 - base);
            if (lane < cnt) {
                unsigned sv = srcs[base + lane];
                float v = elr[sv] + ern; v = v > 0.f ? v : 0.2f * v;
                s_ws[wslot][lane] = make_uint2(sv, __float_as_uint(__expf(v)));
            }
            asm volatile("s_waitcnt lgkmcnt(0)" ::: "memory");
#pragma unroll 4
            for (int j4 = 0; j4 < cnt; j4 += 4) {
                int jj = j4 + quarter;
                int jjc = jj < cnt ? jj : 0;
                uint2 sw = s_ws[wslot][jjc];
                float wv = (jj < cnt) ? __uint_as_float(sw.y) : 0.f;
                den += wv;
                uint2 u = *(const uint2*)(featc + (((size_t)sw.x << 7) + laneoff));
                acc[0] += wv * __uint_as_float(u.x << 16);
                acc[1] += wv * __uint_as_float(u.x & 0xffff0000u);
                acc[2] += wv * __uint_as_float(u.y << 16);
                acc[3] += wv * __uint_as_float(u.y & 0xffff0000u);
            }
        }
#pragma unroll
        for (int f = 0; f < 4; f++) {
            acc[f] += __shfl_xor(acc[f], 16);
            acc[f] += __shfl_xor(acc[f], 32);
        }
        den += __shfl_xor(den, 16);
        den += __shfl_xor(den, 32);
        if (den > 0.f) {
            float inv = 1.f / den;
#pragma unroll
            for (int f = 0; f < 4; f++) res[f] += acc[f] * inv;
        }
    }
    if (quarter == 0) {
        int c = sub * 4;
        float4 o;
        o.x = res[0] + bias[c] + bias[64 + c];
        o.y = res[1] + bias[c + 1] + bias[64 + c + 1];
        o.z = res[2] + bias[c + 2] + bias[64 + c + 2];
        o.w = res[3] + bias[c + 3] + bias[64 + c + 3];
        *(float4*)(outp + (size_t)n * 64 + c) = o;
    }
}

// ---------------- launch ----------------
extern "C" void kernel_launch(void* const* d_in, const int* in_sizes, int n_in,
                              void* d_out, int out_size, void* d_ws, size_t ws_size,
                              hipStream_t stream) {
    const float* x   = (const float*)d_in[0];
    const float* W1  = (const float*)d_in[1];
    const float* al1 = (const float*)d_in[2];
    const float* ar1 = (const float*)d_in[3];
    const float* b1  = (const float*)d_in[4];
    const float* W2  = (const float*)d_in[5];
    const float* al2 = (const float*)d_in[6];
    const float* ar2 = (const float*)d_in[7];
    const float* b2  = (const float*)d_in[8];
    const int* src   = (const int*)d_in[9];
    const int* dst   = (const int*)d_in[10];

    const int N = in_sizes[0] / 128;   // 50000
    const int E = in_sizes[9] / 2;     // 800000
    float* out = (float*)d_out;

    char* w = (char*)d_ws;
    unsigned short* xb   = (unsigned short*)w; w += (size_t)N * 128 * 2;
    unsigned short* feat = (unsigned short*)w; w += (size_t)2 * N * 128 * 2;  // [2][N][M]
    unsigned short* h1b  = (unsigned short*)w; w += (size_t)N * 128 * 2;
    unsigned short* wt1  = (unsigned short*)w; w += (size_t)2 * 128 * 128 * 2;
    unsigned short* wt2  = (unsigned short*)w; w += (size_t)2 * 64 * 128 * 2;
    float* el      = (float*)w; w += (size_t)2 * N * 4 * 4;
    float* er      = (float*)w; w += (size_t)2 * N * 4 * 4;
    unsigned* cnt  = (unsigned*)w; w += (size_t)2 * N * 4;   // counts -> cursor
    unsigned* off  = (unsigned*)w; w += (size_t)2 * (N + 1) * 4;
    unsigned* bsum = (unsigned*)w; w += 2 * 64 * 4;
    unsigned short* csr_src = (unsigned short*)w; w += (size_t)2 * E * 2;

    auto cdiv = [](long long a, long long b) { return (int)((a + b - 1) / b); };
    const int NB = cdiv(N, SCAN_B);

    // ---- fused prep: prepx + prepw + zero cnt ----
    const int nbx = cdiv((long long)N * 16, 256);       // 3125
    const int nbw = cdiv(49152, 256);                   // 192
    const int nbz = cdiv(2LL * N, 256);                 // 391
    k_prep<<<nbx + nbw + nbz, 256, 0, stream>>>(x, xb, N * 16, W1, W2, wt1, wt2, cnt, 2 * N, nbx, nbw);

    // ---- CSR build ----
    { dim3 g(32 * 8, 2); k_histp<<<g, 256, 0, stream>>>(dst, cnt, E, N); }
    { dim3 g(NB, 2); k_scanA<<<g, 256, 0, stream>>>(cnt, bsum, N, NB); }
    { dim3 g(NB, 2); k_scanC2<<<g, 256, 0, stream>>>(cnt, bsum, off, N, NB); }

    // ---- fused scatter (partitioned, NT payload stores) + layer-1 GEMM ----
    const int scatBlocks = NCH * 8 * 2;                 // 1024
    const int gemmBlocks = cdiv(N, 64) * 2;
    k_scatgemm<<<scatBlocks + gemmBlocks, 256, 0, stream>>>(
        src, dst, cnt, csr_src, E, N, scatBlocks, xb, wt1, al1, ar1, feat, el, er);

    // ---- layer 1 aggregate ----
    k_node_gat1<1><<<cdiv(N, 4), 256, 0, stream>>>(off, csr_src, el, er,
        feat, feat + (size_t)N * 128, b1, (unsigned*)h1b, N, E);

    // ---- layer 2 ----
    { dim3 g(cdiv(N, 64), 2);
      k_gemm2<<<g, 256, 0, stream>>>(h1b, wt2, al2, ar2, feat, el, er, N); }
    k_node_gat2<<<cdiv(N, 4), 256, 0, stream>>>(off, csr_src, el, er,
        feat, feat + (size_t)N * 64, b2, out, N, E);
}

// Round 18
// 239.050 us; speedup vs baseline: 1.0693x; 1.0693x over previous
//
#include <hip/hip_runtime.h>
#include <hip/hip_bf16.h>
#include <math.h>

using bf16x8 = __attribute__((ext_vector_type(8))) short;
using f32x4  = __attribute__((ext_vector_type(4))) float;
using v4i    = __attribute__((ext_vector_type(4))) int;

#define NCH 32  // edge chunks per partition (r16-proven; 64 regressed in r17)
#define SCAN_B 1024

__device__ __forceinline__ float b2f(unsigned short u) {
    return __uint_as_float(((unsigned)u) << 16);
}
__device__ __forceinline__ unsigned short f2b(float f) {
    unsigned u = __float_as_uint(f);
    return (unsigned short)((u + 0x7fff + ((u >> 16) & 1)) >> 16);
}

// ---------------- fused prep: x->bf16, W->bf16^T, zero cnt ----------------
__global__ void k_prep(const float* __restrict__ x, unsigned short* __restrict__ xb, int n8,
                       const float* __restrict__ W1, const float* __restrict__ W2,
                       unsigned short* __restrict__ wt1, unsigned short* __restrict__ wt2,
                       unsigned* __restrict__ cnt, int ncnt, int nbx, int nbw) {
    int bid = blockIdx.x;
    if (bid < nbx) {
        int i = bid * 256 + threadIdx.x;
        if (i >= n8) return;
        float4 a = ((const float4*)x)[i * 2], b = ((const float4*)x)[i * 2 + 1];
        uint4 o;
        o.x = f2b(a.x) | ((unsigned)f2b(a.y) << 16);
        o.y = f2b(a.z) | ((unsigned)f2b(a.w) << 16);
        o.z = f2b(b.x) | ((unsigned)f2b(b.y) << 16);
        o.w = f2b(b.z) | ((unsigned)f2b(b.w) << 16);
        ((uint4*)xb)[i] = o;
    } else if (bid < nbx + nbw) {
        int i = (bid - nbx) * 256 + threadIdx.x;
        if (i < 32768) {
            int r = i >> 14, c = (i >> 7) & 127, k = i & 127;
            wt1[i] = f2b(W1[(r << 14) + (k << 7) + c]);
        } else {
            int j = i - 32768;
            if (j >= 16384) return;
            int r = j >> 13, c = (j >> 7) & 63, k = j & 127;
            wt2[j] = f2b(W2[r * 8192 + k * 64 + c]);
        }
    } else {
        int i = (bid - nbx - nbw) * 256 + threadIdx.x;
        if (i < ncnt) cnt[i] = 0u;
    }
}

// ---------------- histogram: XCD-partitioned, LDS-staged counts, coalesced flush ----------------
__global__ __launch_bounds__(256) void k_histp(const int* __restrict__ dst,
                                               unsigned* __restrict__ cnt, int E, int N) {
    __shared__ unsigned sm[6250];  // N/8 counters
    const int part = blockIdx.x & 7, chunk = blockIdx.x >> 3;
    const int r = blockIdx.y;
    const int P = N / 8;
    const int lo = part * P;
    for (int i = threadIdx.x; i < P; i += 256) sm[i] = 0u;
    __syncthreads();
    const int per = E / 32;
    const int e0 = chunk * per, e1 = e0 + per;
    const int* dr = dst + (size_t)r * E;
    for (int e = e0 + (int)threadIdx.x * 4; e < e1; e += 1024) {
        v4i d4 = *(const v4i*)(dr + e);
        int a0 = d4.x - lo, a1 = d4.y - lo, a2 = d4.z - lo, a3 = d4.w - lo;
        if ((unsigned)a0 < (unsigned)P) atomicAdd(&sm[a0], 1u);
        if ((unsigned)a1 < (unsigned)P) atomicAdd(&sm[a1], 1u);
        if ((unsigned)a2 < (unsigned)P) atomicAdd(&sm[a2], 1u);
        if ((unsigned)a3 < (unsigned)P) atomicAdd(&sm[a3], 1u);
    }
    __syncthreads();
    unsigned* cr = cnt + (size_t)r * N + lo;
    for (int i = threadIdx.x; i < P; i += 256) {
        unsigned v = sm[i];
        if (v) atomicAdd(&cr[i], v);
    }
}

// ---------------- scanA: per-1024-chunk sums ----------------
__global__ void k_scanA(const unsigned* __restrict__ cnt, unsigned* __restrict__ bsum,
                        int n, int nb) {
    int r = blockIdx.y, b = blockIdx.x;
    int i0 = b * SCAN_B;
    unsigned s = 0;
    for (int t = threadIdx.x; t < SCAN_B; t += 256) {
        int i = i0 + t;
        if (i < n) s += cnt[(size_t)r * n + i];
    }
    __shared__ unsigned red[256];
    red[threadIdx.x] = s; __syncthreads();
    for (int st = 128; st > 0; st >>= 1) {
        if ((int)threadIdx.x < st) red[threadIdx.x] += red[threadIdx.x + st];
        __syncthreads();
    }
    if (threadIdx.x == 0) bsum[r * nb + b] = red[0];
}

// ---------------- scanC2: inline block-prefix (scanB folded) + off + cursors ----------------
__global__ void k_scanC2(unsigned* __restrict__ cnt, const unsigned* __restrict__ bsum,
                         unsigned* __restrict__ off, int n, int nb) {
    int r = blockIdx.y, b = blockIdx.x;
    __shared__ unsigned sbase[65];
    if (threadIdx.x < 64) {
        int l = threadIdx.x;
        unsigned orig = (l < nb) ? bsum[r * nb + l] : 0u;
        unsigned v = orig;
        for (int st = 1; st < 64; st <<= 1) {
            unsigned t = __shfl_up(v, st);
            if (l >= st) v += t;
        }
        sbase[l] = v - orig;
        if (l == 63) sbase[64] = v;
    }
    __syncthreads();
    if (b == 0 && threadIdx.x == 0) off[(size_t)r * (n + 1) + n] = sbase[64];
    const unsigned base = sbase[b];
    int i0 = b * SCAN_B + (int)threadIdx.x * 4;
    unsigned v[4]; unsigned s = 0;
#pragma unroll
    for (int j = 0; j < 4; j++) {
        int i = i0 + j;
        v[j] = (i < n) ? cnt[(size_t)r * n + i] : 0u;
        s += v[j];
    }
    __shared__ unsigned red[256];
    red[threadIdx.x] = s; __syncthreads();
    for (int st = 1; st < 256; st <<= 1) {
        unsigned t = ((int)threadIdx.x >= st) ? red[threadIdx.x - st] : 0u;
        __syncthreads();
        red[threadIdx.x] += t;
        __syncthreads();
    }
    unsigned run = base + red[threadIdx.x] - s;
#pragma unroll
    for (int j = 0; j < 4; j++) {
        int i = i0 + j;
        if (i < n) {
            off[(size_t)r * (n + 1) + i] = run;
            cnt[(size_t)r * n + i] = run;  // cursor = absolute start slot
        }
        run += v[j];
    }
}

// ---------------- scatter body (XCD-partitioned, global cursors, NT u16 payload) ----------------
__device__ __forceinline__ void scat_body(int bid, const int* __restrict__ src,
                                          const int* __restrict__ dst, unsigned* __restrict__ cur,
                                          unsigned short* __restrict__ csr, int E, int N) {
    const int part = bid & 7;
    const int q = bid >> 3;
    const int r = q & 1, chunk = q >> 1;
    const int lo = part * (N / 8), hi = lo + N / 8;
    const int per = E / NCH;
    const int e0 = chunk * per, e1 = e0 + per;
    const int* dr = dst + (size_t)r * E;
    const int* sr = src + (size_t)r * E;
    unsigned* curr = cur + (size_t)r * N;
    unsigned short* csrr = csr + (size_t)r * E;
    for (int e = e0 + (int)threadIdx.x * 4; e < e1; e += 1024) {
        v4i d4 = *(const v4i*)(dr + e);
        bool m0 = (d4.x >= lo) & (d4.x < hi);
        bool m1 = (d4.y >= lo) & (d4.y < hi);
        bool m2 = (d4.z >= lo) & (d4.z < hi);
        bool m3 = (d4.w >= lo) & (d4.w < hi);
        if (m0 | m1 | m2 | m3) {
            v4i s4 = *(const v4i*)(sr + e);
            if (m0) { unsigned p = atomicAdd(&curr[d4.x], 1u);
                      __builtin_nontemporal_store((unsigned short)s4.x, &csrr[p]); }
            if (m1) { unsigned p = atomicAdd(&curr[d4.y], 1u);
                      __builtin_nontemporal_store((unsigned short)s4.y, &csrr[p]); }
            if (m2) { unsigned p = atomicAdd(&curr[d4.z], 1u);
                      __builtin_nontemporal_store((unsigned short)s4.z, &csrr[p]); }
            if (m3) { unsigned p = atomicAdd(&curr[d4.w], 1u);
                      __builtin_nontemporal_store((unsigned short)s4.w, &csrr[p]); }
        }
    }
}

// ---------------- MFMA GEMM body + fused el/er (LDS-staged) ----------------
template <int M, int H>
__device__ __forceinline__ void gemm_body(int xblk, int r,
        const unsigned short* __restrict__ Xb, const unsigned short* __restrict__ Wt0,
        const float* __restrict__ alv, const float* __restrict__ arv,
        unsigned short* __restrict__ feat0, float* __restrict__ el, float* __restrict__ er,
        int N, unsigned short* xs, unsigned short* ws) {
    constexpr int D = M / H;
    const unsigned short* Wt = Wt0 + (size_t)r * M * 128;
    unsigned short* outp = feat0 + (size_t)r * N * M;
    float* elr = el + (size_t)r * N * H;
    float* err = er + (size_t)r * N * H;
    const int tid = threadIdx.x;
    const int row0 = xblk * 64;
    for (int ch = tid; ch < 64 * 16; ch += 256) {
        int rr = ch >> 4, c16 = ch & 15;
        int gr = row0 + rr;
        uint4 v = make_uint4(0, 0, 0, 0);
        if (gr < N) v = ((const uint4*)(Xb + (size_t)gr * 128))[c16];
        int byte = rr * 256 + ((c16 * 16) ^ ((rr & 7) << 4));
        *(uint4*)((char*)xs + byte) = v;
    }
    for (int ch = tid; ch < M * 16; ch += 256) {
        int rr = ch >> 4, c16 = ch & 15;
        uint4 v = ((const uint4*)(Wt + (size_t)rr * 128))[c16];
        int byte = rr * 256 + ((c16 * 16) ^ ((rr & 7) << 4));
        *(uint4*)((char*)ws + byte) = v;
    }
    __syncthreads();
    const int w = tid >> 6, l = tid & 63;
    const int sub = l & 15;
    const int ar_ = w * 16 + sub;
    const int kg = l >> 4;
    bf16x8 a[4];
#pragma unroll
    for (int k4 = 0; k4 < 4; k4++) {
        int byte = ar_ * 256 + (((kg * 16) + k4 * 64) ^ ((ar_ & 7) << 4));
        a[k4] = *(const bf16x8*)((const char*)xs + byte);
    }
    float alr[M / 16], arr[M / 16];
#pragma unroll
    for (int ct = 0; ct < M / 16; ct++) {
        alr[ct] = alv[(size_t)r * M + ct * 16 + sub];
        arr[ct] = arv[(size_t)r * M + ct * 16 + sub];
    }
    float pel[H][4], per[H][4];
#pragma unroll
    for (int h = 0; h < H; h++)
#pragma unroll
        for (int q = 0; q < 4; q++) { pel[h][q] = 0.f; per[h][q] = 0.f; }

#pragma unroll
    for (int ct = 0; ct < M / 16; ct++) {
        f32x4 acc = {0.f, 0.f, 0.f, 0.f};
        const int bc = ct * 16 + sub;
#pragma unroll
        for (int k4 = 0; k4 < 4; k4++) {
            int byte = bc * 256 + (((kg * 16) + k4 * 64) ^ ((bc & 7) << 4));
            bf16x8 bfr = *(const bf16x8*)((const char*)ws + byte);
            acc = __builtin_amdgcn_mfma_f32_16x16x32_bf16(a[k4], bfr, acc, 0, 0, 0);
        }
        const int hct = (ct * 16) / D;
#pragma unroll
        for (int q = 0; q < 4; q++) {
            pel[hct][q] += acc[q] * alr[ct];
            per[hct][q] += acc[q] * arr[ct];
        }
#pragma unroll
        for (int q = 0; q < 4; q++) {
            int gr = row0 + w * 16 + kg * 4 + q;
            if (gr < N) outp[(size_t)gr * M + ct * 16 + sub] = f2b(acc[q]);
        }
    }
#pragma unroll
    for (int h = 0; h < H; h++)
#pragma unroll
        for (int q = 0; q < 4; q++) {
            float v = pel[h][q], u = per[h][q];
#pragma unroll
            for (int o = 8; o > 0; o >>= 1) { v += __shfl_xor(v, o); u += __shfl_xor(u, o); }
            pel[h][q] = v; per[h][q] = u;
        }
#pragma unroll
    for (int h = 0; h < H; h++) {
        if (sub == h) {
#pragma unroll
            for (int q = 0; q < 4; q++) {
                int gr = row0 + w * 16 + kg * 4 + q;
                if (gr < N) { elr[(size_t)gr * H + h] = pel[h][q]; err[(size_t)gr * H + h] = per[h][q]; }
            }
        }
    }
}

// ---------------- fused scatter + layer-1 GEMM ----------------
__global__ __launch_bounds__(256) void k_scatgemm(
    const int* __restrict__ src, const int* __restrict__ dst,
    unsigned* __restrict__ cur, unsigned short* __restrict__ csr, int E, int N, int scatBlocks,
    const unsigned short* __restrict__ Xb, const unsigned short* __restrict__ Wt0,
    const float* __restrict__ alv, const float* __restrict__ arv,
    unsigned short* __restrict__ feat0, float* __restrict__ el, float* __restrict__ er) {
    __shared__ __align__(16) unsigned short xs[64 * 128];
    __shared__ __align__(16) unsigned short ws[128 * 128];
    int bid = blockIdx.x;
    if (bid < scatBlocks) {
        scat_body(bid, src, dst, cur, csr, E, N);
    } else {
        int g = bid - scatBlocks;
        gemm_body<128, 4>(g >> 1, g & 1, Xb, Wt0, alv, arv, feat0, el, er, N, xs, ws);
    }
}

// ---------------- layer-2 GEMM ----------------
__global__ __launch_bounds__(256) void k_gemm2(
    const unsigned short* __restrict__ Xb, const unsigned short* __restrict__ Wt0,
    const float* __restrict__ alv, const float* __restrict__ arv,
    unsigned short* __restrict__ feat0, float* __restrict__ el, float* __restrict__ er, int N) {
    __shared__ __align__(16) unsigned short xs[64 * 128];
    __shared__ __align__(16) unsigned short ws[64 * 128];
    gemm_body<64, 1>(blockIdx.x, blockIdx.y, Xb, Wt0, alv, arv, feat0, el, er, N, xs, ws);
}

// ---------------- fused per-node GAT, layer 1 (H=4, D=32) ----------------
template <int ELUF>
__global__ __launch_bounds__(256) void k_node_gat1(
    const unsigned* __restrict__ off, const unsigned short* __restrict__ csr_src,
    const float* __restrict__ el, const float* __restrict__ er,
    const unsigned short* __restrict__ feat0, const unsigned short* __restrict__ feat1,
    const float* __restrict__ bias, unsigned* __restrict__ outp, int N, int E) {
    constexpr int H = 4, HD = 128;
    __shared__ float s_w[4][4 * 64];
    __shared__ int s_sid[4][64];
    const int wslot = threadIdx.x >> 6;
    const int lane = threadIdx.x & 63;
    const int n = (blockIdx.x * 256 + threadIdx.x) >> 6;
    if (n >= N) return;
    const int c0 = lane * 2;
    const int h = c0 / 32;
    const unsigned laneoff = (unsigned)lane << 2;

    float res[2] = {0.f, 0.f};

    for (int r = 0; r < 2; r++) {
        const char* __restrict__ featc = (const char*)(r ? feat1 : feat0);
        const float* elr = el + (size_t)r * N * H;
        const float* ernp = er + (size_t)r * N * H + (size_t)n * H;
        float ern[H];
#pragma unroll
        for (int hh = 0; hh < H; hh++) ern[hh] = ernp[hh];
        const unsigned* offr = off + (size_t)r * (N + 1);
        const unsigned short* srcs = csr_src + (size_t)r * E;
        const unsigned o0 = offr[n], o1 = offr[n + 1];

        float den = 0.f;
        float acc[2] = {0.f, 0.f};

        for (unsigned base = o0; base < o1; base += 64) {
            const int cnt = (int)min(64u, o1 - base);
            if (lane < cnt) {
                unsigned sv = srcs[base + lane];
                s_sid[wslot][lane] = (int)sv;
                float4 e4 = *(const float4*)(elr + (size_t)sv * 4);
                float v0 = e4.x + ern[0]; v0 = v0 > 0.f ? v0 : 0.2f * v0;
                float v1 = e4.y + ern[1]; v1 = v1 > 0.f ? v1 : 0.2f * v1;
                float v2 = e4.z + ern[2]; v2 = v2 > 0.f ? v2 : 0.2f * v2;
                float v3 = e4.w + ern[3]; v3 = v3 > 0.f ? v3 : 0.2f * v3;
                float4 wv = make_float4(__expf(v0), __expf(v1), __expf(v2), __expf(v3));
                *(float4*)&s_w[wslot][lane * 4] = wv;
            }
            asm volatile("s_waitcnt lgkmcnt(0)" ::: "memory");
#pragma unroll 8
            for (int j = 0; j < cnt; j++) {
                unsigned sv = (unsigned)s_sid[wslot][j];
                float wv = s_w[wslot][j * 4 + h];
                den += wv;
                unsigned u = *(const unsigned*)(featc + ((sv << 8) + laneoff));
                acc[0] += wv * __uint_as_float(u << 16);
                acc[1] += wv * __uint_as_float(u & 0xffff0000u);
            }
        }
        if (den > 0.f) {
            float inv = 1.f / den;
            res[0] += acc[0] * inv;
            res[1] += acc[1] * inv;
        }
    }
    float v0 = res[0] + bias[c0] + bias[HD + c0];
    float v1 = res[1] + bias[c0 + 1] + bias[HD + c0 + 1];
    if (ELUF) { v0 = v0 > 0.f ? v0 : expm1f(v0); v1 = v1 > 0.f ? v1 : expm1f(v1); }
    outp[((size_t)n * HD + c0) / 2] = f2b(v0) | ((unsigned)f2b(v1) << 16);
}

// ---------------- fused per-node GAT, layer 2 (H=1, D=64) — quad-processed ----------------
__global__ __launch_bounds__(256) void k_node_gat2(
    const unsigned* __restrict__ off, const unsigned short* __restrict__ csr_src,
    const float* __restrict__ el, const float* __restrict__ er,
    const unsigned short* __restrict__ feat0, const unsigned short* __restrict__ feat1,
    const float* __restrict__ bias, float* __restrict__ outp, int N, int E) {
    __shared__ uint2 s_ws[4][64];  // {sid, w}
    const int wslot = threadIdx.x >> 6;
    const int lane = threadIdx.x & 63;
    const int n = (blockIdx.x * 256 + threadIdx.x) >> 6;
    if (n >= N) return;
    const int sub = lane & 15, quarter = lane >> 4;
    const unsigned laneoff = (unsigned)sub << 3;  // 4 cols (8B) per lane

    float res[4] = {0.f, 0.f, 0.f, 0.f};

    for (int r = 0; r < 2; r++) {
        const char* __restrict__ featc = (const char*)(r ? feat1 : feat0);
        const float* elr = el + (size_t)r * N;
        const float ern = er[(size_t)r * N + n];
        const unsigned* offr = off + (size_t)r * (N + 1);
        const unsigned short* srcs = csr_src + (size_t)r * E;
        const unsigned o0 = offr[n], o1 = offr[n + 1];

        float den = 0.f;
        float acc[4] = {0.f, 0.f, 0.f, 0.f};

        for (unsigned base = o0; base < o1; base += 64) {
            const int cnt = (int)min(64u, o1 - base);
            if (lane < cnt) {
                unsigned sv = srcs[base + lane];
                float v = elr[sv] + ern; v = v > 0.f ? v : 0.2f * v;
                s_ws[wslot][lane] = make_uint2(sv, __float_as_uint(__expf(v)));
            }
            asm volatile("s_waitcnt lgkmcnt(0)" ::: "memory");
#pragma unroll 4
            for (int j4 = 0; j4 < cnt; j4 += 4) {
                int jj = j4 + quarter;
                int jjc = jj < cnt ? jj : 0;
                uint2 sw = s_ws[wslot][jjc];
                float wv = (jj < cnt) ? __uint_as_float(sw.y) : 0.f;
                den += wv;
                uint2 u = *(const uint2*)(featc + (((size_t)sw.x << 7) + laneoff));
                acc[0] += wv * __uint_as_float(u.x << 16);
                acc[1] += wv * __uint_as_float(u.x & 0xffff0000u);
                acc[2] += wv * __uint_as_float(u.y << 16);
                acc[3] += wv * __uint_as_float(u.y & 0xffff0000u);
            }
        }
#pragma unroll
        for (int f = 0; f < 4; f++) {
            acc[f] += __shfl_xor(acc[f], 16);
            acc[f] += __shfl_xor(acc[f], 32);
        }
        den += __shfl_xor(den, 16);
        den += __shfl_xor(den, 32);
        if (den > 0.f) {
            float inv = 1.f / den;
#pragma unroll
            for (int f = 0; f < 4; f++) res[f] += acc[f] * inv;
        }
    }
    if (quarter == 0) {
        int c = sub * 4;
        float4 o;
        o.x = res[0] + bias[c] + bias[64 + c];
        o.y = res[1] + bias[c + 1] + bias[64 + c + 1];
        o.z = res[2] + bias[c + 2] + bias[64 + c + 2];
        o.w = res[3] + bias[c + 3] + bias[64 + c + 3];
        *(float4*)(outp + (size_t)n * 64 + c) = o;
    }
}

// ---------------- launch ----------------
extern "C" void kernel_launch(void* const* d_in, const int* in_sizes, int n_in,
                              void* d_out, int out_size, void* d_ws, size_t ws_size,
                              hipStream_t stream) {
    const float* x   = (const float*)d_in[0];
    const float* W1  = (const float*)d_in[1];
    const float* al1 = (const float*)d_in[2];
    const float* ar1 = (const float*)d_in[3];
    const float* b1  = (const float*)d_in[4];
    const float* W2  = (const float*)d_in[5];
    const float* al2 = (const float*)d_in[6];
    const float* ar2 = (const float*)d_in[7];
    const float* b2  = (const float*)d_in[8];
    const int* src   = (const int*)d_in[9];
    const int* dst   = (const int*)d_in[10];

    const int N = in_sizes[0] / 128;   // 50000
    const int E = in_sizes[9] / 2;     // 800000
    float* out = (float*)d_out;

    char* w = (char*)d_ws;
    unsigned short* xb   = (unsigned short*)w; w += (size_t)N * 128 * 2;
    unsigned short* feat = (unsigned short*)w; w += (size_t)2 * N * 128 * 2;  // [2][N][M]
    unsigned short* h1b  = (unsigned short*)w; w += (size_t)N * 128 * 2;
    unsigned short* wt1  = (unsigned short*)w; w += (size_t)2 * 128 * 128 * 2;
    unsigned short* wt2  = (unsigned short*)w; w += (size_t)2 * 64 * 128 * 2;
    float* el      = (float*)w; w += (size_t)2 * N * 4 * 4;
    float* er      = (float*)w; w += (size_t)2 * N * 4 * 4;
    unsigned* cnt  = (unsigned*)w; w += (size_t)2 * N * 4;   // counts -> cursor
    unsigned* off  = (unsigned*)w; w += (size_t)2 * (N + 1) * 4;
    unsigned* bsum = (unsigned*)w; w += 2 * 64 * 4;
    unsigned short* csr_src = (unsigned short*)w; w += (size_t)2 * E * 2;

    auto cdiv = [](long long a, long long b) { return (int)((a + b - 1) / b); };
    const int NB = cdiv(N, SCAN_B);

    // ---- fused prep: prepx + prepw + zero cnt ----
    const int nbx = cdiv((long long)N * 16, 256);       // 3125
    const int nbw = cdiv(49152, 256);                   // 192
    const int nbz = cdiv(2LL * N, 256);                 // 391
    k_prep<<<nbx + nbw + nbz, 256, 0, stream>>>(x, xb, N * 16, W1, W2, wt1, wt2, cnt, 2 * N, nbx, nbw);

    // ---- CSR build ----
    { dim3 g(32 * 8, 2); k_histp<<<g, 256, 0, stream>>>(dst, cnt, E, N); }
    { dim3 g(NB, 2); k_scanA<<<g, 256, 0, stream>>>(cnt, bsum, N, NB); }
    { dim3 g(NB, 2); k_scanC2<<<g, 256, 0, stream>>>(cnt, bsum, off, N, NB); }

    // ---- fused scatter (partitioned, NT payload stores) + layer-1 GEMM ----
    const int scatBlocks = NCH * 8 * 2;                 // 512
    const int gemmBlocks = cdiv(N, 64) * 2;
    k_scatgemm<<<scatBlocks + gemmBlocks, 256, 0, stream>>>(
        src, dst, cnt, csr_src, E, N, scatBlocks, xb, wt1, al1, ar1, feat, el, er);

    // ---- layer 1 aggregate ----
    k_node_gat1<1><<<cdiv(N, 4), 256, 0, stream>>>(off, csr_src, el, er,
        feat, feat + (size_t)N * 128, b1, (unsigned*)h1b, N, E);

    // ---- layer 2 ----
    { dim3 g(cdiv(N, 64), 2);
      k_gemm2<<<g, 256, 0, stream>>>(h1b, wt2, al2, ar2, feat, el, er, N); }
    k_node_gat2<<<cdiv(N, 4), 256, 0, stream>>>(off, csr_src, el, er,
        feat, feat + (size_t)N * 64, b2, out, N, E);
}